// Round 1
// baseline (144.493 us; speedup 1.0000x reference)
//
#include <hip/hip_runtime.h>

typedef __attribute__((ext_vector_type(8))) short bf16x8;
typedef __attribute__((ext_vector_type(4))) float f32x4;

__device__ __forceinline__ short f2bf(float f) {
    union { float f; unsigned u; } v; v.f = f;
    unsigned r = v.u + 0x7fffu + ((v.u >> 16) & 1u);
    return (short)(r >> 16);
}

// ---- prep: centers -> bf16 (pre-swizzled rows) + c_sq; W -> bf16 [128][1024] ----
__global__ __launch_bounds__(256) void rbf_prep(
    const float* __restrict__ centers, const float* __restrict__ W,
    short* __restrict__ c_bf, short* __restrict__ Wb, float* __restrict__ c_sq)
{
    const int tid = threadIdx.x;
    const int lane = tid & 63;
    const int w = tid >> 6;
    const int bid = blockIdx.x;
    if (bid < 256) {
        const int row = bid * 4 + w;               // 0..1023
        const float4 v = ((const float4*)(centers + (size_t)row * 256))[lane];
        float s = v.x*v.x + v.y*v.y + v.z*v.z + v.w*v.w;
        #pragma unroll
        for (int off = 32; off >= 1; off >>= 1) s += __shfl_xor(s, off, 64);
        if (lane == 0) c_sq[row] = s;
        short4 p;
        p.x = f2bf(v.x); p.y = f2bf(v.y); p.z = f2bf(v.z); p.w = f2bf(v.w);
        // pre-swizzled so a LINEAR copy into LDS yields the XOR-swizzled layout
        *(short4*)((char*)c_bf + (size_t)row * 512 + ((lane * 8) ^ ((row & 7) << 4))) = p;
    } else {
        const int b2 = bid - 256;                  // 0..7
        #pragma unroll
        for (int i = 0; i < 16; ++i) {
            const int idx4 = b2 * 4096 + i * 256 + tid;   // 32768 float4 total
            const float4 v = ((const float4*)W)[idx4];
            short4 p;
            p.x = f2bf(v.x); p.y = f2bf(v.y); p.z = f2bf(v.z); p.w = f2bf(v.w);
            ((short4*)Wb)[idx4] = p;
        }
    }
}

// ---- fused main: per block 64 rows; loop over 16 chunks of 64 centers ----
// GEMM1: cross[64][64] = Xb[64][256] @ Cb[64][256]^T   (mfma 16x16x32 bf16)
// phi   = exp(-sigma*(xsq + csq - 2*cross)) -> bf16 in LDS
// GEMM2: out[64][128] += phi[64][64] @ Wb[mc:mc+64][128] (B-frags direct from global)
__global__ __launch_bounds__(256) void rbf_main(
    const float* __restrict__ x, const float* __restrict__ sigmas,
    const float* __restrict__ bvec, const short* __restrict__ c_bf,
    const short* __restrict__ Wb, const float* __restrict__ c_sq,
    float* __restrict__ out)
{
    __shared__ short Xb[64 * 256];   // 32 KB, XOR-swizzled rows
    __shared__ short Cb[64 * 256];   // 32 KB, XOR-swizzled rows
    __shared__ short Phi[64 * 64];   // 8 KB, XOR-swizzled rows
    __shared__ float XSQ[64];

    const int tid = threadIdx.x;
    const int lane = tid & 63;
    const int w = tid >> 6;          // wave 0..3
    const int wr = w >> 1;           // row half
    const int wc = w & 1;            // col half
    const int l15 = lane & 15;
    const int l4 = lane >> 4;        // 0..3
    const int rowbase = blockIdx.x * 64;

    // ---- stage Xb (fp32 -> bf16, swizzled) + per-row sum of squares ----
    #pragma unroll
    for (int i = 0; i < 16; ++i) {
        const int row = i * 4 + w;   // one full row per wave-iteration (coalesced 1KB)
        const float4 v = ((const float4*)(x + (size_t)(rowbase + row) * 256))[lane];
        float s = v.x*v.x + v.y*v.y + v.z*v.z + v.w*v.w;
        #pragma unroll
        for (int off = 32; off >= 1; off >>= 1) s += __shfl_xor(s, off, 64);
        if (lane == 0) XSQ[row] = s;
        short4 p;
        p.x = f2bf(v.x); p.y = f2bf(v.y); p.z = f2bf(v.z); p.w = f2bf(v.w);
        *(short4*)((char*)Xb + row * 512 + ((lane * 8) ^ ((row & 7) << 4))) = p;
    }
    __syncthreads();

    float xs[2][4];
    #pragma unroll
    for (int rf = 0; rf < 2; ++rf)
        #pragma unroll
        for (int j = 0; j < 4; ++j)
            xs[rf][j] = XSQ[wr*32 + rf*16 + l4*4 + j];

    float bq[4];
    #pragma unroll
    for (int cf = 0; cf < 4; ++cf)
        bq[cf] = bvec[wc*64 + cf*16 + l15];

    // all MFMA-fragment LDS rows are (multiple of 8) + l15  ->  swizzle key is (l15&7)
    const int sfr = (l15 & 7) << 4;
    const char* XbA0 = (const char*)Xb + (wr*32 + l15) * 512;
    const char* XbA1 = XbA0 + 16*512;
    const char* CbB0 = (const char*)Cb + (wc*32 + l15) * 512;
    const char* CbB1 = CbB0 + 16*512;
    const char* PhA0 = (const char*)Phi + (wr*32 + l15) * 128;
    const char* PhA1 = PhA0 + 16*128;
    const int kbyte = l4 * 16;       // (l4*8 bf16)*2 bytes

    f32x4 c2[2][4];
    #pragma unroll
    for (int rf = 0; rf < 2; ++rf)
        #pragma unroll
        for (int cf = 0; cf < 4; ++cf)
            c2[rf][cf] = (f32x4){0.f, 0.f, 0.f, 0.f};

    for (int mc = 0; mc < 1024; mc += 64) {
        // stage Cb: 32KB linear copy (source is pre-swizzled)
        {
            const char* src = (const char*)c_bf + (size_t)mc * 512;
            #pragma unroll
            for (int i = 0; i < 8; ++i) {
                const int off = i * 4096 + tid * 16;
                *(bf16x8*)((char*)Cb + off) = *(const bf16x8*)(src + off);
            }
        }
        __syncthreads();   // Cb ready; also: everyone done with GEMM2(prev) -> Phi safe to overwrite

        // ---- GEMM1 ----
        f32x4 c1[2][2];
        #pragma unroll
        for (int rf = 0; rf < 2; ++rf)
            #pragma unroll
            for (int cf = 0; cf < 2; ++cf)
                c1[rf][cf] = (f32x4){0.f, 0.f, 0.f, 0.f};
        #pragma unroll
        for (int ks = 0; ks < 8; ++ks) {
            const int kb2 = ks * 64 + kbyte;
            const bf16x8 a0 = *(const bf16x8*)(XbA0 + (kb2 ^ sfr));
            const bf16x8 a1 = *(const bf16x8*)(XbA1 + (kb2 ^ sfr));
            const bf16x8 b0 = *(const bf16x8*)(CbB0 + (kb2 ^ sfr));
            const bf16x8 b1 = *(const bf16x8*)(CbB1 + (kb2 ^ sfr));
            c1[0][0] = __builtin_amdgcn_mfma_f32_16x16x32_bf16(a0, b0, c1[0][0], 0, 0, 0);
            c1[0][1] = __builtin_amdgcn_mfma_f32_16x16x32_bf16(a0, b1, c1[0][1], 0, 0, 0);
            c1[1][0] = __builtin_amdgcn_mfma_f32_16x16x32_bf16(a1, b0, c1[1][0], 0, 0, 0);
            c1[1][1] = __builtin_amdgcn_mfma_f32_16x16x32_bf16(a1, b1, c1[1][1], 0, 0, 0);
        }

        // ---- phi + swizzled bf16 write ----
        float cs2[2], sg2[2];
        #pragma unroll
        for (int cf = 0; cf < 2; ++cf) {
            const int m = mc + wc*32 + cf*16 + l15;
            cs2[cf] = c_sq[m];
            sg2[cf] = sigmas[m];
        }
        #pragma unroll
        for (int rf = 0; rf < 2; ++rf) {
            #pragma unroll
            for (int cf = 0; cf < 2; ++cf) {
                #pragma unroll
                for (int j = 0; j < 4; ++j) {
                    const float sqd = xs[rf][j] + cs2[cf] - 2.0f * c1[rf][cf][j];
                    const float p = __expf(-sg2[cf] * sqd);
                    const int r = wr*32 + rf*16 + l4*4 + j;      // C/D layout: row=(lane>>4)*4+reg
                    const int colb = (wc*32 + cf*16 + l15) * 2;  //             col=lane&15
                    *(short*)((char*)Phi + r * 128 + (colb ^ ((r & 7) << 4))) = f2bf(p);
                }
            }
        }
        __syncthreads();   // Phi ready

        // ---- GEMM2 (B-fragments straight from L2-resident Wb) ----
        #pragma unroll
        for (int ks = 0; ks < 2; ++ks) {
            const int kb2 = ks * 64 + kbyte;
            const bf16x8 p0 = *(const bf16x8*)(PhA0 + (kb2 ^ sfr));
            const bf16x8 p1 = *(const bf16x8*)(PhA1 + (kb2 ^ sfr));
            const int km = mc + ks * 32 + l4 * 8;
            #pragma unroll
            for (int cf = 0; cf < 4; ++cf) {
                const bf16x8 wv = *(const bf16x8*)(Wb + (size_t)(wc*64 + cf*16 + l15) * 1024 + km);
                c2[0][cf] = __builtin_amdgcn_mfma_f32_16x16x32_bf16(p0, wv, c2[0][cf], 0, 0, 0);
                c2[1][cf] = __builtin_amdgcn_mfma_f32_16x16x32_bf16(p1, wv, c2[1][cf], 0, 0, 0);
            }
        }
    }

    // ---- epilogue: out = acc + b ----
    #pragma unroll
    for (int rf = 0; rf < 2; ++rf) {
        #pragma unroll
        for (int cf = 0; cf < 4; ++cf) {
            #pragma unroll
            for (int j = 0; j < 4; ++j) {
                const int r = rowbase + wr*32 + rf*16 + l4*4 + j;
                const int o = wc*64 + cf*16 + l15;
                out[(size_t)r * 128 + o] = c2[rf][cf][j] + bq[cf];
            }
        }
    }
}

extern "C" void kernel_launch(void* const* d_in, const int* in_sizes, int n_in,
                              void* d_out, int out_size, void* d_ws, size_t ws_size,
                              hipStream_t stream) {
    (void)in_sizes; (void)n_in; (void)out_size; (void)ws_size;
    const float* x       = (const float*)d_in[0];
    const float* centers = (const float*)d_in[1];
    const float* sigmas  = (const float*)d_in[2];
    const float* W       = (const float*)d_in[3];
    const float* b       = (const float*)d_in[4];
    float* out = (float*)d_out;

    short* c_bf = (short*)d_ws;                 // 1024*256 bf16 = 512 KB (pre-swizzled)
    short* Wb   = c_bf + 1024 * 256;            // 128*1024 bf16 = 256 KB
    float* c_sq = (float*)(Wb + 128 * 1024);    // 4 KB

    rbf_prep<<<264, 256, 0, stream>>>(centers, W, c_bf, Wb, c_sq);
    rbf_main<<<1024, 256, 0, stream>>>(x, sigmas, b, c_bf, Wb, c_sq, out);
}

// Round 2
// 118.881 us; speedup vs baseline: 1.2154x; 1.2154x over previous
//
#include <hip/hip_runtime.h>

typedef __attribute__((ext_vector_type(8))) short bf16x8;
typedef __attribute__((ext_vector_type(4))) float f32x4;

__device__ __forceinline__ short f2bf(float f) {
    union { float f; unsigned u; } v; v.f = f;
    unsigned r = v.u + 0x7fffu + ((v.u >> 16) & 1u);
    return (short)(r >> 16);
}

// ---------------- prep ----------------
// blocks 0..255   : csc[m] = {-sigma, -sigma*||c||^2, 2*sigma, 0}   (4 rows/block)
// blocks 256..383 : centers -> cfrag, MFMA-B fragment order
//                   slot s = [c16][ks][f][lane]: m=c16*64+f*16+(l&15), k=ks*32+(l>>4)*8
// blocks 384..447 : W -> wfrag, MFMA-B fragment order
//                   slot s = [kc][f][lane]: o=f*16+(l&15), k=kc*32+(l>>4)*8
__global__ __launch_bounds__(256) void rbf_prep(
    const float* __restrict__ centers, const float* __restrict__ sigmas,
    const float* __restrict__ W,
    short* __restrict__ cfrag, short* __restrict__ wfrag, float4* __restrict__ csc)
{
    const int tid = threadIdx.x;
    const int bid = blockIdx.x;
    if (bid < 256) {
        const int lane = tid & 63, w = tid >> 6;
        const int row = bid * 4 + w;
        const float4 v = ((const float4*)(centers + (size_t)row * 256))[lane];
        float s = v.x*v.x + v.y*v.y + v.z*v.z + v.w*v.w;
        #pragma unroll
        for (int off = 32; off >= 1; off >>= 1) s += __shfl_xor(s, off, 64);
        if (lane == 0) {
            const float sg = sigmas[row];
            csc[row] = make_float4(-sg, -sg * s, 2.0f * sg, 0.0f);
        }
    } else if (bid < 384) {
        const int s = (bid - 256) * 256 + tid;               // 0..32767
        const int c16 = s >> 11, ks = (s >> 8) & 7, f = (s >> 6) & 3, lane = s & 63;
        const int m = c16 * 64 + f * 16 + (lane & 15);
        const int k = ks * 32 + (lane >> 4) * 8;
        const float4 a = *(const float4*)(centers + (size_t)m * 256 + k);
        const float4 b = *(const float4*)(centers + (size_t)m * 256 + k + 4);
        bf16x8 t;
        t[0]=f2bf(a.x); t[1]=f2bf(a.y); t[2]=f2bf(a.z); t[3]=f2bf(a.w);
        t[4]=f2bf(b.x); t[5]=f2bf(b.y); t[6]=f2bf(b.z); t[7]=f2bf(b.w);
        ((bf16x8*)cfrag)[s] = t;
    } else {
        const int s = (bid - 384) * 256 + tid;               // 0..16383
        const int kc = s >> 9, f = (s >> 6) & 7, lane = s & 63;
        const int o = f * 16 + (lane & 15);
        const int k = kc * 32 + (lane >> 4) * 8;
        const float4 a = *(const float4*)(W + (size_t)o * 1024 + k);
        const float4 b = *(const float4*)(W + (size_t)o * 1024 + k + 4);
        bf16x8 t;
        t[0]=f2bf(a.x); t[1]=f2bf(a.y); t[2]=f2bf(a.z); t[3]=f2bf(a.w);
        t[4]=f2bf(b.x); t[5]=f2bf(b.y); t[6]=f2bf(b.z); t[7]=f2bf(b.w);
        ((bf16x8*)wfrag)[s] = t;
    }
}

// ---------------- main ----------------
// 64 rows/block, 4 waves in 2x2. X fragments in registers (reused over all 16
// chunks). GEMM1 B-frags + GEMM2 B-frags read directly from L2-resident
// fragment-ordered global buffers. Phi goes through double-buffered LDS:
// exactly ONE barrier per chunk.
__global__ __launch_bounds__(256) void rbf_main(
    const float* __restrict__ x, const float* __restrict__ bvec,
    const short* __restrict__ cfrag, const short* __restrict__ wfrag,
    const float4* __restrict__ csc, float* __restrict__ out)
{
    __shared__ short Phi[2][64 * 64];   // 16 KB, XOR-swizzled rows
    __shared__ float XSQ[64];

    const int tid = threadIdx.x;
    const int lane = tid & 63;
    const int w = tid >> 6, wr = w >> 1, wc = w & 1;
    const int l15 = lane & 15, l4 = lane >> 4;
    const int rowbase = blockIdx.x * 64;

    // ---- X fragments (regs) + row sums of squares ----
    bf16x8 xa[2][8];
    #pragma unroll
    for (int rf = 0; rf < 2; ++rf) {
        const float* xr = x + (size_t)(rowbase + wr*32 + rf*16 + l15) * 256;
        float ss = 0.f;
        #pragma unroll
        for (int ks = 0; ks < 8; ++ks) {
            const float4 a = *(const float4*)(xr + ks*32 + l4*8);
            const float4 b = *(const float4*)(xr + ks*32 + l4*8 + 4);
            ss += a.x*a.x + a.y*a.y + a.z*a.z + a.w*a.w
                + b.x*b.x + b.y*b.y + b.z*b.z + b.w*b.w;
            bf16x8 t;
            t[0]=f2bf(a.x); t[1]=f2bf(a.y); t[2]=f2bf(a.z); t[3]=f2bf(a.w);
            t[4]=f2bf(b.x); t[5]=f2bf(b.y); t[6]=f2bf(b.z); t[7]=f2bf(b.w);
            xa[rf][ks] = t;
        }
        ss += __shfl_xor(ss, 16, 64);   // reduce across l4 groups
        ss += __shfl_xor(ss, 32, 64);
        if (lane < 16) XSQ[wr*32 + rf*16 + l15] = ss;
    }
    __syncthreads();

    float xs[2][4];
    #pragma unroll
    for (int rf = 0; rf < 2; ++rf)
        #pragma unroll
        for (int j = 0; j < 4; ++j)
            xs[rf][j] = XSQ[wr*32 + rf*16 + l4*4 + j];

    float bq[4];
    #pragma unroll
    for (int cf = 0; cf < 4; ++cf)
        bq[cf] = bvec[wc*64 + cf*16 + l15];

    const int sfr = (l15 & 7) << 4;
    const char* PhiRow = (const char*)Phi + (wr*32 + l15) * 128;

    f32x4 c2[2][4];
    #pragma unroll
    for (int rf = 0; rf < 2; ++rf)
        #pragma unroll
        for (int cf = 0; cf < 4; ++cf)
            c2[rf][cf] = (f32x4){0.f, 0.f, 0.f, 0.f};

    int buf = 0;
    for (int mc16 = 0; mc16 < 16; ++mc16) {
        // ---- GEMM1: cross = X @ C^T, B-frags straight from L2 ----
        f32x4 c1[2][2];
        #pragma unroll
        for (int rf = 0; rf < 2; ++rf)
            #pragma unroll
            for (int cf = 0; cf < 2; ++cf)
                c1[rf][cf] = (f32x4){0.f, 0.f, 0.f, 0.f};
        const bf16x8* cb = (const bf16x8*)cfrag + ((size_t)(mc16*8)*4 + wc*2)*64 + lane;
        #pragma unroll
        for (int ks = 0; ks < 8; ++ks) {
            const bf16x8 b0 = cb[ks*256];
            const bf16x8 b1 = cb[ks*256 + 64];
            c1[0][0] = __builtin_amdgcn_mfma_f32_16x16x32_bf16(xa[0][ks], b0, c1[0][0], 0, 0, 0);
            c1[0][1] = __builtin_amdgcn_mfma_f32_16x16x32_bf16(xa[0][ks], b1, c1[0][1], 0, 0, 0);
            c1[1][0] = __builtin_amdgcn_mfma_f32_16x16x32_bf16(xa[1][ks], b0, c1[1][0], 0, 0, 0);
            c1[1][1] = __builtin_amdgcn_mfma_f32_16x16x32_bf16(xa[1][ks], b1, c1[1][1], 0, 0, 0);
        }

        // ---- phi = exp(-sig*xs - sig*cs + 2*sig*cross) -> swizzled bf16 LDS ----
        const float4 q0 = csc[mc16*64 + wc*32 + l15];
        const float4 q1 = csc[mc16*64 + wc*32 + 16 + l15];
        #pragma unroll
        for (int rf = 0; rf < 2; ++rf) {
            #pragma unroll
            for (int cf = 0; cf < 2; ++cf) {
                const float4 q = cf ? q1 : q0;
                #pragma unroll
                for (int j = 0; j < 4; ++j) {
                    const float t = fmaf(q.z, c1[rf][cf][j], fmaf(q.x, xs[rf][j], q.y));
                    const float p = __expf(t);
                    const int r = wr*32 + rf*16 + l4*4 + j;      // C/D: row=(lane>>4)*4+reg
                    const int colb = (wc*32 + cf*16 + l15) * 2;  //      col=lane&15
                    *(short*)((char*)Phi + buf*8192 + r*128 + (colb ^ ((r & 7) << 4))) = f2bf(p);
                }
            }
        }
        __syncthreads();   // the ONLY barrier per chunk (Phi double-buffered)

        // ---- GEMM2: out += Phi @ W^T, B-frags straight from L2 ----
        const bf16x8* wb = (const bf16x8*)wfrag + ((size_t)(mc16*2)*8 + wc*4)*64 + lane;
        #pragma unroll
        for (int ks = 0; ks < 2; ++ks) {
            const char* ph = PhiRow + buf*8192;
            const int kb = ks*64 + l4*16;
            const bf16x8 p0 = *(const bf16x8*)(ph + ((kb ^ sfr)));
            const bf16x8 p1 = *(const bf16x8*)(ph + 16*128 + (kb ^ sfr));
            #pragma unroll
            for (int cf = 0; cf < 4; ++cf) {
                const bf16x8 wv = wb[ks*512 + cf*64];
                c2[0][cf] = __builtin_amdgcn_mfma_f32_16x16x32_bf16(p0, wv, c2[0][cf], 0, 0, 0);
                c2[1][cf] = __builtin_amdgcn_mfma_f32_16x16x32_bf16(p1, wv, c2[1][cf], 0, 0, 0);
            }
        }
        buf ^= 1;
    }

    // ---- epilogue: out = acc + b ----
    #pragma unroll
    for (int rf = 0; rf < 2; ++rf) {
        #pragma unroll
        for (int cf = 0; cf < 4; ++cf) {
            #pragma unroll
            for (int j = 0; j < 4; ++j) {
                const int r = rowbase + wr*32 + rf*16 + l4*4 + j;
                const int o = wc*64 + cf*16 + l15;
                out[(size_t)r * 128 + o] = c2[rf][cf][j] + bq[cf];
            }
        }
    }
}

extern "C" void kernel_launch(void* const* d_in, const int* in_sizes, int n_in,
                              void* d_out, int out_size, void* d_ws, size_t ws_size,
                              hipStream_t stream) {
    (void)in_sizes; (void)n_in; (void)out_size; (void)ws_size;
    const float* x       = (const float*)d_in[0];
    const float* centers = (const float*)d_in[1];
    const float* sigmas  = (const float*)d_in[2];
    const float* W       = (const float*)d_in[3];
    const float* b       = (const float*)d_in[4];
    float* out = (float*)d_out;

    short*  cfrag = (short*)d_ws;                    // 32768*8 bf16 = 512 KB
    short*  wfrag = cfrag + 32768 * 8;               // 16384*8 bf16 = 256 KB
    float4* csc   = (float4*)(wfrag + 16384 * 8);    // 1024*16 B    =  16 KB

    rbf_prep<<<448, 256, 0, stream>>>(centers, sigmas, W, cfrag, wfrag, csc);
    rbf_main<<<1024, 256, 0, stream>>>(x, b, cfrag, wfrag, csc, out);
}

// Round 3
// 110.649 us; speedup vs baseline: 1.3059x; 1.0744x over previous
//
#include <hip/hip_runtime.h>

typedef __attribute__((ext_vector_type(8))) short bf16x8;
typedef __attribute__((ext_vector_type(16))) float f32x16;
typedef unsigned int u32;

#define LOG2E 1.44269504088896f

__device__ __forceinline__ short f2bf(float f) {
    union { float f; unsigned u; } v; v.f = f;
    unsigned r = v.u + 0x7fffu + ((v.u >> 16) & 1u);
    return (short)(r >> 16);
}

#if __has_builtin(__builtin_amdgcn_exp2f)
#define EXP2(x) __builtin_amdgcn_exp2f(x)
#else
#define EXP2(x) __builtin_exp2f(x)
#endif

__device__ __forceinline__ u32 pack_bf16_trunc(float lo, float hi) {
#if __has_builtin(__builtin_amdgcn_perm)
    return __builtin_amdgcn_perm(__float_as_uint(hi), __float_as_uint(lo), 0x07060302u);
#else
    return (__float_as_uint(hi) & 0xFFFF0000u) | (__float_as_uint(lo) >> 16);
#endif
}

__device__ __forceinline__ f32x16 zero16() {
    f32x16 v;
    #pragma unroll
    for (int i = 0; i < 16; ++i) v[i] = 0.f;
    return v;
}

// ---------------- prep ----------------
// blocks 0..255  : per-center scalars (log2e-scaled): ns=-s*L, nscs=-s*||c||^2*L, ts=2s*L
// blocks 256..383: centers -> cfrag, 32x32x16 A-frag order (swapped GEMM1 A = centers)
//                  slot s=[c][ks][lane]: m=c*32+(l&31), k=ks*16+(l>>5)*8
// blocks 384..447: W -> wfrag, 32x32x16 B-frag order (PV B = W^T)
//                  slot s=[c][ct][k2][lane]: o=ct*32+(l&31), m=c*32+k2*16+(l>>5)*8
__global__ __launch_bounds__(256) void rbf_prep(
    const float* __restrict__ centers, const float* __restrict__ sigmas,
    const float* __restrict__ W,
    short* __restrict__ cfrag, short* __restrict__ wfrag,
    float* __restrict__ ns, float* __restrict__ nscs, float* __restrict__ ts)
{
    const int tid = threadIdx.x;
    const int bid = blockIdx.x;
    if (bid < 256) {
        const int lane = tid & 63, w = tid >> 6;
        const int row = bid * 4 + w;
        const float4 v = ((const float4*)(centers + (size_t)row * 256))[lane];
        float s = v.x*v.x + v.y*v.y + v.z*v.z + v.w*v.w;
        #pragma unroll
        for (int off = 32; off >= 1; off >>= 1) s += __shfl_xor(s, off, 64);
        if (lane == 0) {
            const float sg = sigmas[row];
            ns[row]   = -sg * LOG2E;
            nscs[row] = -sg * s * LOG2E;
            ts[row]   = 2.0f * sg * LOG2E;
        }
    } else if (bid < 384) {
        const int s = (bid - 256) * 256 + tid;               // 0..32767
        const int c = s >> 10, ks = (s >> 6) & 15, lane = s & 63;
        const int m = c * 32 + (lane & 31);
        const int k = ks * 16 + (lane >> 5) * 8;
        const float4 a = *(const float4*)(centers + (size_t)m * 256 + k);
        const float4 b = *(const float4*)(centers + (size_t)m * 256 + k + 4);
        bf16x8 t;
        t[0]=f2bf(a.x); t[1]=f2bf(a.y); t[2]=f2bf(a.z); t[3]=f2bf(a.w);
        t[4]=f2bf(b.x); t[5]=f2bf(b.y); t[6]=f2bf(b.z); t[7]=f2bf(b.w);
        ((bf16x8*)cfrag)[s] = t;
    } else {
        const int s = (bid - 384) * 256 + tid;               // 0..16383
        const int c = s >> 9, ct = (s >> 7) & 3, k2 = (s >> 6) & 1, lane = s & 63;
        const int o = ct * 32 + (lane & 31);
        const int m = c * 32 + k2 * 16 + (lane >> 5) * 8;
        const float4 a = *(const float4*)(W + (size_t)o * 1024 + m);
        const float4 b = *(const float4*)(W + (size_t)o * 1024 + m + 4);
        bf16x8 t;
        t[0]=f2bf(a.x); t[1]=f2bf(a.y); t[2]=f2bf(a.z); t[3]=f2bf(a.w);
        t[4]=f2bf(b.x); t[5]=f2bf(b.y); t[6]=f2bf(b.z); t[7]=f2bf(b.w);
        ((bf16x8*)wfrag)[s] = t;
    }
}

// ---------------- main: barrier-free, wave-local ----------------
// Wave owns 32 x-rows x 128 outs. Per chunk (32 centers):
//   S[m][q] = mfma(C,X) x16      (lane: col q=lane&31, row m=crow(r,hi))
//   phi     = exp2(2s'*S - s'*xs - s'*cs)   (all lane-local)
//   pack -> bf16, shfl_xor(32) half-exchange -> PV A-frags
//   acc[ct] += mfma(pa, Wfrag)   x8
// No LDS, no __syncthreads.
__global__ __launch_bounds__(256, 2) void rbf_main(
    const float* __restrict__ x, const float* __restrict__ bvec,
    const short* __restrict__ cfrag, const short* __restrict__ wfrag,
    const float* __restrict__ ns, const float* __restrict__ nscs,
    const float* __restrict__ ts, float* __restrict__ out)
{
    const int tid = threadIdx.x;
    const int lane = tid & 63;
    const int l31 = lane & 31;
    const int hi = lane >> 5;
    const int wvid = blockIdx.x * 4 + (tid >> 6);  // 0..2047
    const int qb = wvid * 32;

    // ---- X fragments (B-operand: lane holds X[q=qb+l31][k=ks*16+hi*8+j]) + xs ----
    bf16x8 xb[16];
    const float* xr = x + (size_t)(qb + l31) * 256 + hi * 8;
    float ss = 0.f;
    #pragma unroll
    for (int ks = 0; ks < 16; ++ks) {
        const float4 a = *(const float4*)(xr + ks * 16);
        const float4 b = *(const float4*)(xr + ks * 16 + 4);
        ss += a.x*a.x + a.y*a.y + a.z*a.z + a.w*a.w
            + b.x*b.x + b.y*b.y + b.z*b.z + b.w*b.w;
        bf16x8 t;
        t[0]=f2bf(a.x); t[1]=f2bf(a.y); t[2]=f2bf(a.z); t[3]=f2bf(a.w);
        t[4]=f2bf(b.x); t[5]=f2bf(b.y); t[6]=f2bf(b.z); t[7]=f2bf(b.w);
        xb[ks] = t;
    }
    ss += __shfl_xor(ss, 32, 64);   // partner holds the other half of row q
    const float xs = ss;

    f32x16 acc[4];
    #pragma unroll
    for (int ct = 0; ct < 4; ++ct) acc[ct] = zero16();

    for (int c = 0; c < 32; ++c) {
        // W B-frags: issued a full S-phase ahead of use -> latency hidden
        bf16x8 wf[4][2];
        #pragma unroll
        for (int ct = 0; ct < 4; ++ct)
            #pragma unroll
            for (int k2 = 0; k2 < 2; ++k2)
                wf[ct][k2] = ((const bf16x8*)wfrag)[((c * 4 + ct) * 2 + k2) * 64 + lane];

        // ---- S = C-chunk . X^T  (swapped: lane-local phi rows) ----
        f32x16 S = zero16();
        const bf16x8* cb = (const bf16x8*)cfrag + (size_t)c * 1024 + lane;
        #pragma unroll
        for (int ks = 0; ks < 16; ++ks)
            S = __builtin_amdgcn_mfma_f32_32x32x16_bf16(cb[ks * 64], xb[ks], S, 0, 0, 0);

        // ---- phi: reg r -> m-offset 8*(r>>2) + 4*hi + (r&3) ----
        float p[16];
        #pragma unroll
        for (int g = 0; g < 4; ++g) {
            const float4 a4 = *(const float4*)(ns   + c * 32 + g * 8 + hi * 4);
            const float4 b4 = *(const float4*)(nscs + c * 32 + g * 8 + hi * 4);
            const float4 c4 = *(const float4*)(ts   + c * 32 + g * 8 + hi * 4);
            const float* ap = (const float*)&a4;
            const float* bp = (const float*)&b4;
            const float* cp = (const float*)&c4;
            #pragma unroll
            for (int j = 0; j < 4; ++j) {
                const float t = fmaf(cp[j], S[g * 4 + j], fmaf(ap[j], xs, bp[j]));
                p[g * 4 + j] = EXP2(t);
            }
        }

        // ---- pack + half-exchange -> PV A-frags; accumulate ----
        #pragma unroll
        for (int k2 = 0; k2 < 2; ++k2) {
            const int rb = k2 * 8;
            // quad g=2*k2:   hi=0 -> ko{0..3};  hi=1 -> ko{4..7}   (A,B)
            // quad g=2*k2+1: hi=0 -> ko{8..11}; hi=1 -> ko{12..15} (C,D)
            const u32 A = pack_bf16_trunc(p[rb + 0], p[rb + 1]);
            const u32 B = pack_bf16_trunc(p[rb + 2], p[rb + 3]);
            const u32 C = pack_bf16_trunc(p[rb + 4], p[rb + 5]);
            const u32 D = pack_bf16_trunc(p[rb + 6], p[rb + 7]);
            // lane needs: hi=0: {A,B | partner A,B}; hi=1: {partner C,D | C,D}
            const u32 g0 = hi ? A : C;
            const u32 g1 = hi ? B : D;
            const u32 r0 = (u32)__shfl_xor((int)g0, 32, 64);
            const u32 r1 = (u32)__shfl_xor((int)g1, 32, 64);
            union { u32 u[4]; bf16x8 v; } pa;
            pa.u[0] = hi ? r0 : A;
            pa.u[1] = hi ? r1 : B;
            pa.u[2] = hi ? C : r0;
            pa.u[3] = hi ? D : r1;
            #pragma unroll
            for (int ct = 0; ct < 4; ++ct)
                acc[ct] = __builtin_amdgcn_mfma_f32_32x32x16_bf16(pa.v, wf[ct][k2], acc[ct], 0, 0, 0);
        }
    }

    // ---- epilogue: out[q][o] = acc + b ; D layout: col=l31=o-offset, row=crow(r,hi)=q-offset ----
    float bq[4];
    #pragma unroll
    for (int ct = 0; ct < 4; ++ct) bq[ct] = bvec[ct * 32 + l31];
    #pragma unroll
    for (int r = 0; r < 16; ++r) {
        const int q = qb + (r & 3) + 8 * (r >> 2) + 4 * hi;
        #pragma unroll
        for (int ct = 0; ct < 4; ++ct)
            out[(size_t)q * 128 + ct * 32 + l31] = acc[ct][r] + bq[ct];
    }
}

extern "C" void kernel_launch(void* const* d_in, const int* in_sizes, int n_in,
                              void* d_out, int out_size, void* d_ws, size_t ws_size,
                              hipStream_t stream) {
    (void)in_sizes; (void)n_in; (void)out_size; (void)ws_size;
    const float* x       = (const float*)d_in[0];
    const float* centers = (const float*)d_in[1];
    const float* sigmas  = (const float*)d_in[2];
    const float* W       = (const float*)d_in[3];
    const float* b       = (const float*)d_in[4];
    float* out = (float*)d_out;

    short* cfrag = (short*)d_ws;                 // 32768 frags * 16B = 512 KB
    short* wfrag = cfrag + 32768 * 8;            // 16384 frags * 16B = 256 KB
    float* ns    = (float*)(wfrag + 16384 * 8);  // 4 KB
    float* nscs  = ns + 1024;                    // 4 KB
    float* ts    = nscs + 1024;                  // 4 KB

    rbf_prep<<<448, 256, 0, stream>>>(centers, sigmas, W, cfrag, wfrag, ns, nscs, ts);
    rbf_main<<<512, 256, 0, stream>>>(x, b, cfrag, wfrag, ns, nscs, ts, out);
}

// Round 4
// 86.106 us; speedup vs baseline: 1.6781x; 1.2850x over previous
//
#include <hip/hip_runtime.h>

typedef __attribute__((ext_vector_type(8))) short bf16x8;
typedef __attribute__((ext_vector_type(16))) float f32x16;
typedef unsigned int u32;

#define LOG2E 1.44269504088896f

__device__ __forceinline__ short f2bf(float f) {
    union { float f; unsigned u; } v; v.f = f;
    unsigned r = v.u + 0x7fffu + ((v.u >> 16) & 1u);
    return (short)(r >> 16);
}

#if __has_builtin(__builtin_amdgcn_exp2f)
#define EXP2(x) __builtin_amdgcn_exp2f(x)
#else
#define EXP2(x) __builtin_exp2f(x)
#endif

__device__ __forceinline__ u32 pack_bf16_trunc(float lo, float hi) {
#if __has_builtin(__builtin_amdgcn_perm)
    return __builtin_amdgcn_perm(__float_as_uint(hi), __float_as_uint(lo), 0x07060302u);
#else
    return (__float_as_uint(hi) & 0xFFFF0000u) | (__float_as_uint(lo) >> 16);
#endif
}

__device__ __forceinline__ f32x16 zero16() {
    f32x16 v;
    #pragma unroll
    for (int i = 0; i < 16; ++i) v[i] = 0.f;
    return v;
}

// ---------------- prep (unchanged from round 3; layouts verified absmax=0) ----------------
// blocks 0..255  : per-center scalars (log2e-scaled): ns=-s*L, nscs=-s*||c||^2*L, ts=2s*L
// blocks 256..383: centers -> cfrag, 32x32x16 A-frag order: slot s=[c][ks][lane]
// blocks 384..447: W -> wfrag, 32x32x16 B-frag order: slot s=[c][ct][k2][lane]
__global__ __launch_bounds__(256) void rbf_prep(
    const float* __restrict__ centers, const float* __restrict__ sigmas,
    const float* __restrict__ W,
    short* __restrict__ cfrag, short* __restrict__ wfrag,
    float* __restrict__ ns, float* __restrict__ nscs, float* __restrict__ ts)
{
    const int tid = threadIdx.x;
    const int bid = blockIdx.x;
    if (bid < 256) {
        const int lane = tid & 63, w = tid >> 6;
        const int row = bid * 4 + w;
        const float4 v = ((const float4*)(centers + (size_t)row * 256))[lane];
        float s = v.x*v.x + v.y*v.y + v.z*v.z + v.w*v.w;
        #pragma unroll
        for (int off = 32; off >= 1; off >>= 1) s += __shfl_xor(s, off, 64);
        if (lane == 0) {
            const float sg = sigmas[row];
            ns[row]   = -sg * LOG2E;
            nscs[row] = -sg * s * LOG2E;
            ts[row]   = 2.0f * sg * LOG2E;
        }
    } else if (bid < 384) {
        const int s = (bid - 256) * 256 + tid;               // 0..32767
        const int c = s >> 10, ks = (s >> 6) & 15, lane = s & 63;
        const int m = c * 32 + (lane & 31);
        const int k = ks * 16 + (lane >> 5) * 8;
        const float4 a = *(const float4*)(centers + (size_t)m * 256 + k);
        const float4 b = *(const float4*)(centers + (size_t)m * 256 + k + 4);
        bf16x8 t;
        t[0]=f2bf(a.x); t[1]=f2bf(a.y); t[2]=f2bf(a.z); t[3]=f2bf(a.w);
        t[4]=f2bf(b.x); t[5]=f2bf(b.y); t[6]=f2bf(b.z); t[7]=f2bf(b.w);
        ((bf16x8*)cfrag)[s] = t;
    } else {
        const int s = (bid - 384) * 256 + tid;               // 0..16383
        const int c = s >> 9, ct = (s >> 7) & 3, k2 = (s >> 6) & 1, lane = s & 63;
        const int o = ct * 32 + (lane & 31);
        const int m = c * 32 + k2 * 16 + (lane >> 5) * 8;
        const float4 a = *(const float4*)(W + (size_t)o * 1024 + m);
        const float4 b = *(const float4*)(W + (size_t)o * 1024 + m + 4);
        bf16x8 t;
        t[0]=f2bf(a.x); t[1]=f2bf(a.y); t[2]=f2bf(a.z); t[3]=f2bf(a.w);
        t[4]=f2bf(b.x); t[5]=f2bf(b.y); t[6]=f2bf(b.z); t[7]=f2bf(b.w);
        ((bf16x8*)wfrag)[s] = t;
    }
}

// ---------------- main: wave-local compute + block-shared LDS operand staging ----------------
// 512 blocks x 4 waves; wave owns 32 q-rows x 128 outs (identical mapping to round 3).
// Per chunk (32 centers): issue next chunk's global loads -> S = mfma(Cb_lds, xb_regs)
// -> phi -> pack/shfl -> PV with Wb_lds -> ds_write staged -> ONE barrier.
__global__ __launch_bounds__(256, 2) void rbf_main(
    const float* __restrict__ x, const float* __restrict__ bvec,
    const short* __restrict__ cfrag, const short* __restrict__ wfrag,
    const float* __restrict__ ns, const float* __restrict__ nscs,
    const float* __restrict__ ts, float* __restrict__ out)
{
    __shared__ short Cb[2][8192];   // 16 KB per buffer: 16 frags (ks) x 1 KB
    __shared__ short Wb[2][4096];   //  8 KB per buffer: 8 frags (ct,k2) x 1 KB

    const int tid = threadIdx.x;
    const int lane = tid & 63;
    const int l31 = lane & 31;
    const int hi = lane >> 5;
    const int w = tid >> 6;
    const int qb = blockIdx.x * 128 + w * 32;

    // ---- issue chunk-0 staging loads first (latency hides under X prologue) ----
    bf16x8 st0, st1, st2, st3, st4, st5;
    {
        const bf16x8* cs = (const bf16x8*)cfrag;
        const bf16x8* wsrc = (const bf16x8*)wfrag;
        st0 = cs[tid]; st1 = cs[256 + tid]; st2 = cs[512 + tid]; st3 = cs[768 + tid];
        st4 = wsrc[tid]; st5 = wsrc[256 + tid];
    }

    // ---- X fragments (B-operand, regs) + xs ----
    bf16x8 xb[16];
    const float* xr = x + (size_t)(qb + l31) * 256 + hi * 8;
    float ss = 0.f;
    #pragma unroll
    for (int ks = 0; ks < 16; ++ks) {
        const float4 a = *(const float4*)(xr + ks * 16);
        const float4 b = *(const float4*)(xr + ks * 16 + 4);
        ss += a.x*a.x + a.y*a.y + a.z*a.z + a.w*a.w
            + b.x*b.x + b.y*b.y + b.z*b.z + b.w*b.w;
        bf16x8 t;
        t[0]=f2bf(a.x); t[1]=f2bf(a.y); t[2]=f2bf(a.z); t[3]=f2bf(a.w);
        t[4]=f2bf(b.x); t[5]=f2bf(b.y); t[6]=f2bf(b.z); t[7]=f2bf(b.w);
        xb[ks] = t;
    }
    ss += __shfl_xor(ss, 32, 64);
    const float xs = ss;

    // ---- commit chunk 0 to LDS buffer 0 ----
    ((bf16x8*)Cb[0])[tid] = st0;       ((bf16x8*)Cb[0])[256 + tid] = st1;
    ((bf16x8*)Cb[0])[512 + tid] = st2; ((bf16x8*)Cb[0])[768 + tid] = st3;
    ((bf16x8*)Wb[0])[tid] = st4;       ((bf16x8*)Wb[0])[256 + tid] = st5;
    __syncthreads();

    f32x16 acc[4];
    #pragma unroll
    for (int ct = 0; ct < 4; ++ct) acc[ct] = zero16();

    int buf = 0;
    for (int c = 0; c < 32; ++c) {
        // ---- issue next chunk's staging loads (consumed after PV) ----
        const int cn = (c < 31) ? c + 1 : 31;
        {
            const bf16x8* cs = (const bf16x8*)cfrag + (size_t)cn * 1024;
            const bf16x8* wsrc = (const bf16x8*)wfrag + (size_t)cn * 512;
            st0 = cs[tid]; st1 = cs[256 + tid]; st2 = cs[512 + tid]; st3 = cs[768 + tid];
            st4 = wsrc[tid]; st5 = wsrc[256 + tid];
        }

        // ---- S = C-chunk . X^T  (A from LDS, B from regs) ----
        f32x16 S = zero16();
        const bf16x8* cbl = (const bf16x8*)Cb[buf] + lane;
        #pragma unroll
        for (int ks = 0; ks < 16; ++ks)
            S = __builtin_amdgcn_mfma_f32_32x32x16_bf16(cbl[ks * 64], xb[ks], S, 0, 0, 0);

        // ---- phi: reg r -> m-offset 8*(r>>2) + 4*hi + (r&3) ----
        float p[16];
        #pragma unroll
        for (int g = 0; g < 4; ++g) {
            const float4 a4 = *(const float4*)(ns   + c * 32 + g * 8 + hi * 4);
            const float4 b4 = *(const float4*)(nscs + c * 32 + g * 8 + hi * 4);
            const float4 c4 = *(const float4*)(ts   + c * 32 + g * 8 + hi * 4);
            const float* ap = (const float*)&a4;
            const float* bp = (const float*)&b4;
            const float* cp = (const float*)&c4;
            #pragma unroll
            for (int j = 0; j < 4; ++j) {
                const float t = fmaf(cp[j], S[g * 4 + j], fmaf(ap[j], xs, bp[j]));
                p[g * 4 + j] = EXP2(t);
            }
        }

        // ---- pack + half-exchange -> PV A-frags; accumulate (B from LDS) ----
        const bf16x8* wbl = (const bf16x8*)Wb[buf] + lane;
        #pragma unroll
        for (int k2 = 0; k2 < 2; ++k2) {
            const int rb = k2 * 8;
            const u32 A = pack_bf16_trunc(p[rb + 0], p[rb + 1]);
            const u32 B = pack_bf16_trunc(p[rb + 2], p[rb + 3]);
            const u32 C = pack_bf16_trunc(p[rb + 4], p[rb + 5]);
            const u32 D = pack_bf16_trunc(p[rb + 6], p[rb + 7]);
            const u32 g0 = hi ? A : C;
            const u32 g1 = hi ? B : D;
            const u32 r0 = (u32)__shfl_xor((int)g0, 32, 64);
            const u32 r1 = (u32)__shfl_xor((int)g1, 32, 64);
            union { u32 u[4]; bf16x8 v; } pa;
            pa.u[0] = hi ? r0 : A;
            pa.u[1] = hi ? r1 : B;
            pa.u[2] = hi ? C : r0;
            pa.u[3] = hi ? D : r1;
            #pragma unroll
            for (int ct = 0; ct < 4; ++ct)
                acc[ct] = __builtin_amdgcn_mfma_f32_32x32x16_bf16(pa.v, wbl[(ct * 2 + k2) * 64], acc[ct], 0, 0, 0);
        }

        // ---- commit staged chunk to the other buffer; one barrier per chunk ----
        ((bf16x8*)Cb[buf ^ 1])[tid] = st0;       ((bf16x8*)Cb[buf ^ 1])[256 + tid] = st1;
        ((bf16x8*)Cb[buf ^ 1])[512 + tid] = st2; ((bf16x8*)Cb[buf ^ 1])[768 + tid] = st3;
        ((bf16x8*)Wb[buf ^ 1])[tid] = st4;       ((bf16x8*)Wb[buf ^ 1])[256 + tid] = st5;
        __syncthreads();
        buf ^= 1;
    }

    // ---- epilogue: out[q][o] = acc + b ----
    float bq[4];
    #pragma unroll
    for (int ct = 0; ct < 4; ++ct) bq[ct] = bvec[ct * 32 + l31];
    #pragma unroll
    for (int r = 0; r < 16; ++r) {
        const int q = qb + (r & 3) + 8 * (r >> 2) + 4 * hi;
        #pragma unroll
        for (int ct = 0; ct < 4; ++ct)
            out[(size_t)q * 128 + ct * 32 + l31] = acc[ct][r] + bq[ct];
    }
}

extern "C" void kernel_launch(void* const* d_in, const int* in_sizes, int n_in,
                              void* d_out, int out_size, void* d_ws, size_t ws_size,
                              hipStream_t stream) {
    (void)in_sizes; (void)n_in; (void)out_size; (void)ws_size;
    const float* x       = (const float*)d_in[0];
    const float* centers = (const float*)d_in[1];
    const float* sigmas  = (const float*)d_in[2];
    const float* W       = (const float*)d_in[3];
    const float* b       = (const float*)d_in[4];
    float* out = (float*)d_out;

    short* cfrag = (short*)d_ws;                 // 32768 frags * 16B = 512 KB
    short* wfrag = cfrag + 32768 * 8;            // 16384 frags * 16B = 256 KB
    float* ns    = (float*)(wfrag + 16384 * 8);  // 4 KB
    float* nscs  = ns + 1024;                    // 4 KB
    float* ts    = nscs + 1024;                  // 4 KB

    rbf_prep<<<448, 256, 0, stream>>>(centers, sigmas, W, cfrag, wfrag, ns, nscs, ts);
    rbf_main<<<512, 256, 0, stream>>>(x, b, cfrag, wfrag, ns, nscs, ts, out);
}